// Round 1
// 566.336 us; speedup vs baseline: 1.0057x; 1.0057x over previous
//
#include <hip/hip_runtime.h>

// GBDT split histogram + cumsum.
// X: [N=1e6, F=100] int32 bins in [0,256); gradient, hessian: [N] f32.
// out = concat(Gl[1,F,256], Hl[1,F,256]), Gl[f,b] = sum_i g[i]*(X[i,f] <= b).
//
// R5 -> R6: K1's atomic phase is at the ds_add_u64 rate floor (1e8 lane-ops
// ~ 163 us @ 1 cyc/lane/CU; occupancy 48.5%->100% in R5 was neutral, so the
// ~19 us over floor is NOT wave supply). Attack the remaining overhead:
//  - flush: 5.2M device-scope u64 atomicAdds (102-way cross-XCD contention,
//    serialized kernel tail) -> replaced by plain coalesced u64 stores of the
//    packed per-chunk histogram into part[C][F*BINS] (20.9 MB, ~3 us).
//  - zero_kernel deleted (part is fully overwritten, no init needed).
//  - K2 fused reduce+scan: 100 blocks, lane=bin -> coalesced partial loads,
//    decodes packed (g,h) once, scans both planes in one block.
// Numerics: per-chunk packed u64 sums exact (h-sum/bin ~ 38*2^20 << 2^32,
// |g-sum| << 2^31, h>=0 so no lo->hi carry); cross-chunk reduce in s64/u64.
// Fixed-point 2^20 quantization unchanged from R5 (passed absmax check).
// Timed-region budget: ~376 us harness poison/restore (fixed) + K1 + ~8 us K2.

#define F     100
#define FG    20      // features per block group
#define NG    5       // groups tiling the 100-feature row (80 B, int4-clean)
#define BINS  256
#define TPB   1024
#define RPI   (TPB / 5)     // 204 rows per block-iteration (threads 1020-1023 idle)
#define CCHUNKS 102         // 5*102 = 510 blocks = 2 per CU exactly
#define SCALE_F 1048576.0f  // 2^20
#define INV_SCALE (1.0 / 1048576.0)

__global__ __launch_bounds__(TPB) void hist_part_kernel(
    const int* __restrict__ X, const float* __restrict__ grad,
    const float* __restrict__ hess, unsigned long long* __restrict__ part,
    int N, int rows_per_chunk)
{
    // hi32 = sum g*2^20 (wraps as s32), lo32 = sum h*2^20 (u32, no carry-out)
    __shared__ unsigned long long hist[FG * BINS];   // 40960 B -> 2 blocks/CU
    const int tid  = threadIdx.x;
    const int c    = blockIdx.x / NG;
    const int grp  = blockIdx.x % NG;
    const int col0 = grp * FG;

    for (int i = tid; i < FG * BINS; i += TPB) hist[i] = 0ULL;
    __syncthreads();

    int r0 = c * rows_per_chunk;
    int r1 = r0 + rows_per_chunk;
    if (r1 > N) r1 = N;

    const int s = tid % 5;        // which int4 of the 80 B segment
    const int q = tid / 5;        // row-within-tile

    if (q < RPI) {
        const int fb = (4 * s) * BINS;   // plane base for features 4s..4s+3
        const char* xb = (const char*)(X + col0 + 4 * s);

        int r = r0 + q;
        if (r < r1) {
            int4 cur = *(const int4*)(xb + (size_t)r * (F * 4));
            int  gq  = __float2int_rn(grad[r] * SCALE_F);
            int  hq  = __float2int_rn(hess[r] * SCALE_F);
            unsigned long long vc =
                ((unsigned long long)(unsigned int)gq << 32) | (unsigned int)hq;
            for (int rn = r + RPI; rn < r1; rn += RPI) {
                int4 nxt = *(const int4*)(xb + (size_t)rn * (F * 4));
                int  gn  = __float2int_rn(grad[rn] * SCALE_F);
                int  hn  = __float2int_rn(hess[rn] * SCALE_F);
                unsigned long long vn =
                    ((unsigned long long)(unsigned int)gn << 32) | (unsigned int)hn;
                atomicAdd(&hist[fb + 0 * BINS + cur.x], vc);
                atomicAdd(&hist[fb + 1 * BINS + cur.y], vc);
                atomicAdd(&hist[fb + 2 * BINS + cur.z], vc);
                atomicAdd(&hist[fb + 3 * BINS + cur.w], vc);
                cur = nxt; vc = vn;
            }
            atomicAdd(&hist[fb + 0 * BINS + cur.x], vc);
            atomicAdd(&hist[fb + 1 * BINS + cur.y], vc);
            atomicAdd(&hist[fb + 2 * BINS + cur.z], vc);
            atomicAdd(&hist[fb + 3 * BINS + cur.w], vc);
        }
    }
    __syncthreads();

    // Flush: plain coalesced stores of the packed per-chunk histogram.
    // part layout: [c][F*BINS]; this block owns the [col0*BINS, col0*BINS+FG*BINS)
    // slice of row c. hist[i] corresponds to feature col0+i/BINS, bin i%BINS,
    // i.e. part-row offset col0*BINS + i.  No atomics, no zero-init needed.
    unsigned long long* dst = part + (size_t)c * (F * BINS) + (size_t)col0 * BINS;
    for (int i = tid; i < FG * BINS; i += TPB) dst[i] = hist[i];
}

__global__ __launch_bounds__(BINS) void reduce_scan_kernel(
    const unsigned long long* __restrict__ part, float* __restrict__ out)
{
    // One block per feature; lane = bin. Coalesced reduction over CCHUNKS
    // partials (each wave reads 512 contiguous bytes per c), then a
    // Hillis-Steele scan of both planes in one pass.
    __shared__ float sg[BINS];
    __shared__ float sh[BINS];
    const int b = threadIdx.x;
    const int f = blockIdx.x;

    long long          gs = 0;
    unsigned long long hs = 0;
    const unsigned long long* p = part + (size_t)f * BINS + b;
#pragma unroll 4
    for (int c = 0; c < CCHUNKS; ++c) {
        unsigned long long v = p[(size_t)c * (F * BINS)];
        gs += (long long)(int)(v >> 32);            // sign-extend g field
        hs += (unsigned long long)(unsigned int)v;  // h field
    }
    sg[b] = (float)((double)gs * INV_SCALE);
    sh[b] = (float)((double)hs * INV_SCALE);
    __syncthreads();
#pragma unroll
    for (int off = 1; off < BINS; off <<= 1) {
        float tg = (b >= off) ? sg[b - off] : 0.0f;
        float th = (b >= off) ? sh[b - off] : 0.0f;
        __syncthreads();
        sg[b] += tg;
        sh[b] += th;
        __syncthreads();
    }
    out[(size_t)f * BINS + b]             = sg[b];   // Gl plane
    out[(size_t)(F + f) * BINS + b]       = sh[b];   // Hl plane
}

extern "C" void kernel_launch(void* const* d_in, const int* in_sizes, int n_in,
                              void* d_out, int out_size, void* d_ws, size_t ws_size,
                              hipStream_t stream)
{
    const int*   X = (const int*)d_in[0];
    const float* g = (const float*)d_in[1];
    const float* h = (const float*)d_in[2];
    float*              out  = (float*)d_out;
    unsigned long long* part = (unsigned long long*)d_ws;  // C*F*BINS u64 = 20.9 MB
    const int N = in_sizes[1];

    const int C   = CCHUNKS;
    const int rpc = (N + C - 1) / C;

    hipLaunchKernelGGL(hist_part_kernel, dim3(NG * C), dim3(TPB), 0, stream,
                       X, g, h, part, N, rpc);
    hipLaunchKernelGGL(reduce_scan_kernel, dim3(F), dim3(BINS), 0, stream,
                       part, out);
}